// Round 2
// baseline (537.114 us; speedup 1.0000x reference)
//
#include <hip/hip_runtime.h>
#include <hip/hip_bf16.h>
#include <stdint.h>

#define B_DIM 8192
#define IN_DIMC 1024
#define HIDC 1024
#define K_DIM 1024
#define ODE_STEPS 6

typedef float f32x4 __attribute__((ext_vector_type(4)));
typedef short bf16x8 __attribute__((ext_vector_type(8)));
typedef unsigned short u16x8 __attribute__((ext_vector_type(8)));

__device__ __forceinline__ float bf2f(unsigned short u) {
    union { unsigned int u; float f; } c; c.u = ((unsigned int)u) << 16; return c.f;
}
__device__ __forceinline__ unsigned short f2bf(float f) {
    union { float f; unsigned int u; } c; c.f = f;
    unsigned int u = c.u;
    return (unsigned short)((u + 0x7fffu + ((u >> 16) & 1u)) >> 16);
}
__device__ __forceinline__ float fast_tanh(float x) {
    float e = __expf(2.0f * x);
    return 1.0f - 2.0f / (e + 1.0f);
}

// ---------------- convert all f32 inputs to bf16 in workspace ----------------
constexpr size_t XN    = (size_t)B_DIM * IN_DIMC;
constexpr size_t HN    = (size_t)B_DIM * HIDC;
constexpr size_t WINN  = (size_t)HIDC * IN_DIMC;
constexpr size_t WRECN = (size_t)HIDC * HIDC;
constexpr size_t WGN   = (size_t)HIDC * (IN_DIMC + HIDC);
constexpr size_t TOTQ  = (XN + HN + WINN + WRECN + WGN) / 4;

__global__ __launch_bounds__(256) void convert_all(
    const float* __restrict__ x, const float* __restrict__ h,
    const float* __restrict__ win, const float* __restrict__ wrec,
    const float* __restrict__ wgate,
    unsigned short* __restrict__ x_bf, unsigned short* __restrict__ h_bf,
    unsigned short* __restrict__ win_bf, unsigned short* __restrict__ wrec_bf,
    unsigned short* __restrict__ wgx_bf, unsigned short* __restrict__ wgh_bf)
{
    size_t q = (size_t)blockIdx.x * 256 + threadIdx.x;
    if (q >= TOTQ) return;
    size_t e = q * 4;
    const float* src; unsigned short* dst; size_t si, di;
    if (e < XN)                          { src = x;    si = e;                       dst = x_bf;    di = si; }
    else if (e < XN + HN)                { src = h;    si = e - XN;                  dst = h_bf;    di = si; }
    else if (e < XN + HN + WINN)         { src = win;  si = e - XN - HN;             dst = win_bf;  di = si; }
    else if (e < XN + HN + WINN + WRECN) { src = wrec; si = e - XN - HN - WINN;      dst = wrec_bf; di = si; }
    else {
        size_t i = e - XN - HN - WINN - WRECN;
        size_t row = i >> 11, col = i & 2047;
        src = wgate; si = i;
        if (col < 1024) { dst = wgx_bf; di = row * 1024 + col; }
        else            { dst = wgh_bf; di = row * 1024 + (col - 1024); }
    }
    float4 v = *(const float4*)(src + si);
    ushort4 o;
    o.x = f2bf(v.x); o.y = f2bf(v.y); o.z = f2bf(v.z); o.w = f2bf(v.w);
    *(ushort4*)(dst + di) = o;
}

// ---- fused dual-GEMM, 8-phase-style pipelined core ----
// BM=256 BN=128 BK=64, 512 threads (8 waves, 4m x 2n, 64x64 wave tile per GEMM).
// Grid = 256 = 1 block/CU exactly. LDS 128 KB double-buffered.
// Per K-tile: 4 phases {issue 2 global_load_lds for t+1 | ds_read quarter ->
// s_barrier -> lgkmcnt(0)+sched_barrier -> setprio(1) 16 MFMA setprio(0) ->
// s_barrier}. Counted vmcnt(2) once per K-tile (never 0 in main loop): the 8
// staging loads of t+1 stay in flight across all 4 phases (T3+T4).
// LDS XOR-swizzle (slot ^= row&7 on 16B slots of 128B rows) applied BOTH
// sides: pre-swizzled per-lane global src for global_load_lds (linear dest)
// + swizzled ds_read addr (rule #21; involution).
// Epilogue state (GX/ID bf16, carried h f32) in accumulator-native layout:
// slot = ((bid*8 + wave)*16 + mi*4+ni)*64 + lane  (16B/lane full-line access).
constexpr int BM = 256, BN = 128, BK = 64;
constexpr int NT = HIDC / BN;           // 8
constexpr int GRID = (B_DIM / BM) * NT; // 256
constexpr int NK = K_DIM / BK;          // 16

__device__ __forceinline__ void gload_lds16(const void* g, void* l) {
    __builtin_amdgcn_global_load_lds(
        (const __attribute__((address_space(1))) void*)g,
        (__attribute__((address_space(3))) void*)l, 16, 0, 0);
}

#define MFMA_BF16 __builtin_amdgcn_mfma_f32_16x16x32_bf16

template<bool STEP>
__global__ __launch_bounds__(512, 2) void ltc_gemm(
    const unsigned short* __restrict__ A,
    const unsigned short* __restrict__ B1,
    const unsigned short* __restrict__ B2,
    const unsigned short* __restrict__ GXID,   // native layout, 8 bf16/slot
    const float* __restrict__ h_init,          // row-major f32 (step 0 only)
    float* __restrict__ h_nat,                 // native f32 state, in-place
    const float* __restrict__ log_tau,
    float* __restrict__ h_out,                 // final step: d_out half 0
    float* __restrict__ h_out2,                // final step: d_out half 1
    unsigned short* __restrict__ hbf_out,      // row-major bf16 (next A)
    const float* __restrict__ bias1, const float* __restrict__ bias2,
    unsigned short* __restrict__ GXID_out)     // pre-kernel output
{
    __shared__ __attribute__((aligned(16))) unsigned short lA [2][BM * BK]; // 64 KB
    __shared__ __attribute__((aligned(16))) unsigned short lB1[2][BN * BK]; // 32 KB
    __shared__ __attribute__((aligned(16))) unsigned short lB2[2][BN * BK]; // 32 KB

    const int tid = threadIdx.x;
    const int w = tid >> 6, l = tid & 63;
    // bijective XCD swizzle (GRID % 8 == 0)
    const int bid = (blockIdx.x & 7) * (GRID / 8) + (blockIdx.x >> 3);
    const int mt = bid / NT, nt = bid % NT;
    const int m0 = mt * BM, n0 = nt * BN;
    const int wm = (w >> 1) * 64, wn = (w & 1) * 64;
    const int lm = l & 15, lq = l >> 4;

    // staging: one wave-load = 8 rows x 128B (full BK row), lane l covers
    // row lrg = l>>3 of the group at swizzled 16B slot lsl = (l&7) ^ lrg.
    const int lrg = l >> 3;
    const int lsl = (l & 7) ^ lrg;
    // wave w stages A rows [w*32, w*32+32) (4 groups), B1/B2 rows [w*16,w*16+16) (2 each)
    const unsigned short* sA  = A  + (size_t)(m0 + w * 32 + lrg) * K_DIM + lsl * 8;
    const unsigned short* sB1 = B1 + (size_t)(n0 + w * 16 + lrg) * K_DIM + lsl * 8;
    const unsigned short* sB2 = B2 + (size_t)(n0 + w * 16 + lrg) * K_DIM + lsl * 8;
    const int loA = w * 2048;   // elem offset: (w*4 groups)*512
    const int loB = w * 1024;   // elem offset: (w*2 groups)*512

    // ds_read swizzled slots: frag (row, ks) reads 16B at slot (ks*4+lq)^(row&7);
    // row&7 == lm&7 for all fragments (row = base16 + lm).
    const int sl0 = lq ^ (lm & 7);
    const int sl1 = (lq + 4) ^ (lm & 7);

    f32x4 acc1[4][4], acc2[4][4];
    f32x4 z4 = {0.f, 0.f, 0.f, 0.f};
    #pragma unroll
    for (int i = 0; i < 4; i++)
        #pragma unroll
        for (int j = 0; j < 4; j++) { acc1[i][j] = z4; acc2[i][j] = z4; }

#define STG_A(Q, KE, R)  gload_lds16(sA  + (size_t)(R) * 8 * K_DIM + (KE), &lA [Q][loA + (R) * 512])
#define STG_B1(Q, KE, R) gload_lds16(sB1 + (size_t)(R) * 8 * K_DIM + (KE), &lB1[Q][loB + (R) * 512])
#define STG_B2(Q, KE, R) gload_lds16(sB2 + (size_t)(R) * 8 * K_DIM + (KE), &lB2[Q][loB + (R) * 512])
#define RDA(P, MI, SL)  (*(const bf16x8*)&lA [P][(wm + (MI) * 16 + lm) * 64 + (SL) * 8])
#define RDB1(P, NI, SL) (*(const bf16x8*)&lB1[P][(wn + (NI) * 16 + lm) * 64 + (SL) * 8])
#define RDB2(P, NI, SL) (*(const bf16x8*)&lB2[P][(wn + (NI) * 16 + lm) * 64 + (SL) * 8])
#define BAR() asm volatile("s_barrier" ::: "memory")
#define LGKM0() do { asm volatile("s_waitcnt lgkmcnt(0)" ::: "memory"); \
                     __builtin_amdgcn_sched_barrier(0); } while (0)

#define CLUSTER(NIA, NIB, AF, U1A, U1B, U2A, U2B)                             \
    __builtin_amdgcn_s_setprio(1);                                            \
    _Pragma("unroll")                                                         \
    for (int mi = 0; mi < 4; mi++) {                                          \
        acc1[mi][NIA] = MFMA_BF16(AF[mi], U1A, acc1[mi][NIA], 0, 0, 0);       \
        acc2[mi][NIA] = MFMA_BF16(AF[mi], U2A, acc2[mi][NIA], 0, 0, 0);       \
        acc1[mi][NIB] = MFMA_BF16(AF[mi], U1B, acc1[mi][NIB], 0, 0, 0);       \
        acc2[mi][NIB] = MFMA_BF16(AF[mi], U2B, acc2[mi][NIB], 0, 0, 0);       \
    }                                                                         \
    __builtin_amdgcn_s_setprio(0);

#define KITER(P, Q, KE, STG)                                                  \
    {                                                                         \
        bf16x8 af[4], u1a, u1b, u2a, u2b;                                     \
        /* ---- phase 0: ks=0, ni 0-1 ---- */                                 \
        if (STG) { STG_A(Q, KE, 0); STG_A(Q, KE, 1);                          \
                   asm volatile("s_waitcnt vmcnt(2)" ::: "memory"); }         \
        else     { asm volatile("s_waitcnt vmcnt(0)" ::: "memory"); }         \
        BAR();                                                                \
        _Pragma("unroll")                                                     \
        for (int mi = 0; mi < 4; mi++) af[mi] = RDA(P, mi, sl0);              \
        u1a = RDB1(P, 0, sl0); u1b = RDB1(P, 1, sl0);                         \
        u2a = RDB2(P, 0, sl0); u2b = RDB2(P, 1, sl0);                         \
        LGKM0();                                                              \
        CLUSTER(0, 1, af, u1a, u1b, u2a, u2b);                                \
        BAR();                                                                \
        /* ---- phase 1: ks=0, ni 2-3 ---- */                                 \
        if (STG) { STG_A(Q, KE, 2); STG_A(Q, KE, 3); }                        \
        u1a = RDB1(P, 2, sl0); u1b = RDB1(P, 3, sl0);                         \
        u2a = RDB2(P, 2, sl0); u2b = RDB2(P, 3, sl0);                         \
        LGKM0();                                                              \
        CLUSTER(2, 3, af, u1a, u1b, u2a, u2b);                                \
        BAR();                                                                \
        /* ---- phase 2: ks=1, ni 0-1 ---- */                                 \
        if (STG) { STG_B1(Q, KE, 0); STG_B1(Q, KE, 1); }                      \
        _Pragma("unroll")                                                     \
        for (int mi = 0; mi < 4; mi++) af[mi] = RDA(P, mi, sl1);              \
        u1a = RDB1(P, 0, sl1); u1b = RDB1(P, 1, sl1);                         \
        u2a = RDB2(P, 0, sl1); u2b = RDB2(P, 1, sl1);                         \
        LGKM0();                                                              \
        CLUSTER(0, 1, af, u1a, u1b, u2a, u2b);                                \
        BAR();                                                                \
        /* ---- phase 3: ks=1, ni 2-3 ---- */                                 \
        if (STG) { STG_B2(Q, KE, 0); STG_B2(Q, KE, 1); }                      \
        u1a = RDB1(P, 2, sl1); u1b = RDB1(P, 3, sl1);                         \
        u2a = RDB2(P, 2, sl1); u2b = RDB2(P, 3, sl1);                         \
        LGKM0();                                                              \
        CLUSTER(2, 3, af, u1a, u1b, u2a, u2b);                                \
        BAR();                                                                \
    }

    // prologue: stage tile 0 into buf 0 (8 loads/wave), no wait
    #pragma unroll
    for (int r = 0; r < 4; r++) STG_A(0, 0, r);
    #pragma unroll
    for (int r = 0; r < 2; r++) { STG_B1(0, 0, r); STG_B2(0, 0, r); }

    for (int t = 0; t < NK - 1; ++t) {
        const int p = t & 1, q = p ^ 1;
        const int ke = (t + 1) * BK;
        KITER(p, q, ke, true);
    }
    KITER(1, 0, 0, false);   // t = NK-1, drains vmcnt to 0

    // epilogue: C/D layout col=lane&15, row=(lane>>4)*4+r  [m89-verified]
    constexpr float subdt = 1.0f / (float)ODE_STEPS;
    const size_t wslot = (((size_t)bid * 8 + w) * 16) * 64 + l;

    float pc1[4], pc2[4];   // per-ni hoisted: scale (STEP) or biases (!STEP)
    #pragma unroll
    for (int ni = 0; ni < 4; ni++) {
        const int gn = n0 + wn + ni * 16 + lm;
        if (STEP) {
            pc1[ni] = subdt * __expf(-log_tau[gn]);
        } else {
            pc1[ni] = bias1[gn];
            pc2[ni] = bias2[gn];
        }
    }

    #pragma unroll
    for (int mi = 0; mi < 4; mi++) {
        #pragma unroll
        for (int ni = 0; ni < 4; ni++) {
            const int gmb = m0 + wm + mi * 16 + lq * 4;
            const int gn  = n0 + wn + ni * 16 + lm;
            const size_t slot = wslot + (size_t)(mi * 4 + ni) * 64;
            if (STEP) {
                const float sc = pc1[ni];
                u16x8 gi = *(const u16x8*)&GXID[slot * 8];
                f32x4 st;
                if (h_init) {
                    #pragma unroll
                    for (int r = 0; r < 4; r++)
                        st[r] = h_init[(size_t)(gmb + r) * HIDC + gn];
                } else {
                    st = *(const f32x4*)&h_nat[slot * 4];
                }
                f32x4 hn;
                #pragma unroll
                for (int r = 0; r < 4; r++) {
                    float gx = bf2f((unsigned short)gi[r])     + acc1[mi][ni][r];
                    float dr = bf2f((unsigned short)gi[4 + r]) + acc2[mi][ni][r];
                    float gt = fast_tanh(dr) / (1.0f + __expf(-gx));
                    hn[r] = fmaf(sc, gt - st[r], st[r]);
                }
                if (h_out) {
                    #pragma unroll
                    for (int r = 0; r < 4; r++) {
                        size_t idx = (size_t)(gmb + r) * HIDC + gn;
                        h_out[idx]  = hn[r];
                        h_out2[idx] = hn[r];
                    }
                } else {
                    *(f32x4*)&h_nat[slot * 4] = hn;
                    #pragma unroll
                    for (int r = 0; r < 4; r++)
                        hbf_out[(size_t)(gmb + r) * HIDC + gn] = f2bf(hn[r]);
                }
            } else {
                u16x8 o;
                #pragma unroll
                for (int r = 0; r < 4; r++) {
                    o[r]     = f2bf(acc1[mi][ni][r] + pc1[ni]);
                    o[4 + r] = f2bf(acc2[mi][ni][r] + pc2[ni]);
                }
                *(u16x8*)&GXID_out[slot * 8] = o;
            }
        }
    }
}

extern "C" void kernel_launch(void* const* d_in, const int* in_sizes, int n_in,
                              void* d_out, int out_size, void* d_ws, size_t ws_size,
                              hipStream_t stream)
{
    const float* x    = (const float*)d_in[0];
    const float* h    = (const float*)d_in[1];
    const float* ltau = (const float*)d_in[2];
    const float* winw = (const float*)d_in[3];
    const float* winb = (const float*)d_in[4];
    const float* wrec = (const float*)d_in[5];
    const float* wg   = (const float*)d_in[6];
    const float* wgb  = (const float*)d_in[7];

    char* ws = (char*)d_ws;
    unsigned short* x_bf    = (unsigned short*)ws; ws += XN * 2;
    unsigned short* h_bf0   = (unsigned short*)ws; ws += HN * 2;
    unsigned short* h_bf1   = (unsigned short*)ws; ws += HN * 2;
    unsigned short* win_bf  = (unsigned short*)ws; ws += WINN * 2;
    unsigned short* wrec_bf = (unsigned short*)ws; ws += WRECN * 2;
    unsigned short* wgx_bf  = (unsigned short*)ws; ws += WINN * 2;
    unsigned short* wgh_bf  = (unsigned short*)ws; ws += WRECN * 2;
    unsigned short* GXID    = (unsigned short*)ws; ws += HN * 2 * 2;  // 32 MB
    float*          h_nat   = (float*)ws;          ws += HN * 4;      // 32 MB

    float* hout  = (float*)d_out;
    float* hout2 = hout + (size_t)B_DIM * HIDC;

    convert_all<<<(int)(TOTQ / 256), 256, 0, stream>>>(
        x, h, winw, wrec, wg, x_bf, h_bf0, win_bf, wrec_bf, wgx_bf, wgh_bf);

    // pre-loop: GXID = pack(x@Wgx^T + wgb, x@Win^T + winb) in native layout
    ltc_gemm<false><<<GRID, 512, 0, stream>>>(
        x_bf, wgx_bf, win_bf,
        nullptr, nullptr, nullptr, nullptr, nullptr, nullptr, nullptr,
        wgb, winb, GXID);

    unsigned short* hbf[2] = {h_bf0, h_bf1};
    for (int s = 0; s < ODE_STEPS; s++) {
        const bool last = (s == ODE_STEPS - 1);
        ltc_gemm<true><<<GRID, 512, 0, stream>>>(
            hbf[s & 1], wgh_bf, wrec_bf,
            GXID,
            (s == 0) ? h : nullptr,
            h_nat, ltau,
            last ? hout : nullptr, last ? hout2 : nullptr,
            last ? nullptr : hbf[(s + 1) & 1],
            nullptr, nullptr, nullptr);
    }
}

// Round 3
// 459.208 us; speedup vs baseline: 1.1697x; 1.1697x over previous
//
#include <hip/hip_runtime.h>
#include <hip/hip_bf16.h>
#include <stdint.h>

#define B_DIM 8192
#define IN_DIMC 1024
#define HIDC 1024
#define K_DIM 1024
#define ODE_STEPS 6

typedef float f32x4 __attribute__((ext_vector_type(4)));
typedef short bf16x8 __attribute__((ext_vector_type(8)));
typedef unsigned short u16x8 __attribute__((ext_vector_type(8)));

__device__ __forceinline__ float bf2f(unsigned short u) {
    union { unsigned int u; float f; } c; c.u = ((unsigned int)u) << 16; return c.f;
}
__device__ __forceinline__ unsigned short f2bf(float f) {
    union { float f; unsigned int u; } c; c.f = f;
    unsigned int u = c.u;
    return (unsigned short)((u + 0x7fffu + ((u >> 16) & 1u)) >> 16);
}
__device__ __forceinline__ float fast_tanh(float x) {
    float e = __expf(2.0f * x);
    return 1.0f - 2.0f / (e + 1.0f);
}

// ---------------- convert all f32 inputs to bf16 in workspace ----------------
constexpr size_t XN    = (size_t)B_DIM * IN_DIMC;
constexpr size_t HN    = (size_t)B_DIM * HIDC;
constexpr size_t WINN  = (size_t)HIDC * IN_DIMC;
constexpr size_t WRECN = (size_t)HIDC * HIDC;
constexpr size_t WGN   = (size_t)HIDC * (IN_DIMC + HIDC);
constexpr size_t TOTQ  = (XN + HN + WINN + WRECN + WGN) / 4;

__global__ __launch_bounds__(256) void convert_all(
    const float* __restrict__ x, const float* __restrict__ h,
    const float* __restrict__ win, const float* __restrict__ wrec,
    const float* __restrict__ wgate,
    unsigned short* __restrict__ x_bf, unsigned short* __restrict__ h_bf,
    unsigned short* __restrict__ win_bf, unsigned short* __restrict__ wrec_bf,
    unsigned short* __restrict__ wgx_bf, unsigned short* __restrict__ wgh_bf)
{
    size_t q = (size_t)blockIdx.x * 256 + threadIdx.x;
    if (q >= TOTQ) return;
    size_t e = q * 4;
    const float* src; unsigned short* dst; size_t si, di;
    if (e < XN)                          { src = x;    si = e;                       dst = x_bf;    di = si; }
    else if (e < XN + HN)                { src = h;    si = e - XN;                  dst = h_bf;    di = si; }
    else if (e < XN + HN + WINN)         { src = win;  si = e - XN - HN;             dst = win_bf;  di = si; }
    else if (e < XN + HN + WINN + WRECN) { src = wrec; si = e - XN - HN - WINN;      dst = wrec_bf; di = si; }
    else {
        size_t i = e - XN - HN - WINN - WRECN;
        size_t row = i >> 11, col = i & 2047;
        src = wgate; si = i;
        if (col < 1024) { dst = wgx_bf; di = row * 1024 + col; }
        else            { dst = wgh_bf; di = row * 1024 + (col - 1024); }
    }
    float4 v = *(const float4*)(src + si);
    ushort4 o;
    o.x = f2bf(v.x); o.y = f2bf(v.y); o.z = f2bf(v.z); o.w = f2bf(v.w);
    *(ushort4*)(dst + di) = o;
}

// ---- fused dual-GEMM: BK=32 quad-buffer, 3-tile-deep prefetch, asm ds_read ----
// BM=256 BN=128 BK=32, 512 threads (8 waves, 4m x 2n, 64x64 wave tile/GEMM).
// Grid = 256 = 1 block/CU. LDS 128 KB = 4 buffers x (A 16K + B1 8K + B2 8K).
// Per tile t: stage tile t+3 (4 gload_lds); vmcnt(12) [tail 8/4/0]; barrier;
// 12 inline-asm ds_read_b128 (opaque to alias analysis -> compiler inserts NO
// vmcnt(0) of its own); lgkmcnt(4)+sched_barrier; 16 MFMA (acc1);
// lgkmcnt(0)+sched_barrier; 16 MFMA (acc2); barrier.  Counted vmcnt gives the
// staging loads ~3 tiles (>1 HBM latency) of slack; never drains in main loop.
// LDS swizzle for 64B rows: 16B-slot ^= (row>>1)&3 -> 2-way bank alias (free).
// Epilogue state (GX/ID bf16, carried h f32) in accumulator-native layout:
// slot = ((bid*8 + wave)*16 + mi*4+ni)*64 + lane  (16B/lane full-line access).
constexpr int BM = 256, BN = 128, BK = 32;
constexpr int NT = HIDC / BN;           // 8
constexpr int GRID = (B_DIM / BM) * NT; // 256
constexpr int NKT = K_DIM / BK;         // 32

__device__ __forceinline__ void gload_lds16(const void* g, void* l) {
    __builtin_amdgcn_global_load_lds(
        (const __attribute__((address_space(1))) void*)g,
        (__attribute__((address_space(3))) void*)l, 16, 0, 0);
}

#define MFMA_BF16 __builtin_amdgcn_mfma_f32_16x16x32_bf16

#define DS_READ(D, A_, O) \
    asm volatile("ds_read_b128 %0, %1 offset:" O : "=v"(D) : "v"(A_))

#define STAGE4(SQ, KE) do {                                                   \
    gload_lds16(sA  + (KE),          &SMEM[(SQ) * 8192 + dA]);                \
    gload_lds16(sA  + 16384 + (KE),  &SMEM[(SQ) * 8192 + dA + 512]);          \
    gload_lds16(sB1 + (KE),          &SMEM[32768 + (SQ) * 4096 + dB]);        \
    gload_lds16(sB2 + (KE),          &SMEM[49152 + (SQ) * 4096 + dB]);        \
} while (0)

#define KITER(P, VM, DO_STG, SQ, KE)                                          \
    {                                                                         \
        if (DO_STG) STAGE4(SQ, KE);                                           \
        asm volatile("s_waitcnt vmcnt(" VM ")" ::: "memory");                 \
        __builtin_amdgcn_sched_barrier(0);                                    \
        asm volatile("s_barrier" ::: "memory");                               \
        bf16x8 a0, a1, a2, a3, x0, x1, x2, x3, y0, y1, y2, y3;                \
        const unsigned aA  = rdA  + (P) * 16384;                              \
        const unsigned aB1 = rdB1 + (P) * 8192;                               \
        const unsigned aB2 = rdB2 + (P) * 8192;                               \
        DS_READ(a0, aA, "0");    DS_READ(a1, aA, "1024");                     \
        DS_READ(a2, aA, "2048"); DS_READ(a3, aA, "3072");                     \
        DS_READ(x0, aB1, "0");    DS_READ(x1, aB1, "1024");                   \
        DS_READ(x2, aB1, "2048"); DS_READ(x3, aB1, "3072");                   \
        DS_READ(y0, aB2, "0");    DS_READ(y1, aB2, "1024");                   \
        DS_READ(y2, aB2, "2048"); DS_READ(y3, aB2, "3072");                   \
        asm volatile("s_waitcnt lgkmcnt(4)" ::: "memory");                    \
        __builtin_amdgcn_sched_barrier(0);                                    \
        __builtin_amdgcn_s_setprio(1);                                        \
        acc1[0][0] = MFMA_BF16(a0, x0, acc1[0][0], 0, 0, 0);                  \
        acc1[1][0] = MFMA_BF16(a1, x0, acc1[1][0], 0, 0, 0);                  \
        acc1[2][0] = MFMA_BF16(a2, x0, acc1[2][0], 0, 0, 0);                  \
        acc1[3][0] = MFMA_BF16(a3, x0, acc1[3][0], 0, 0, 0);                  \
        acc1[0][1] = MFMA_BF16(a0, x1, acc1[0][1], 0, 0, 0);                  \
        acc1[1][1] = MFMA_BF16(a1, x1, acc1[1][1], 0, 0, 0);                  \
        acc1[2][1] = MFMA_BF16(a2, x1, acc1[2][1], 0, 0, 0);                  \
        acc1[3][1] = MFMA_BF16(a3, x1, acc1[3][1], 0, 0, 0);                  \
        acc1[0][2] = MFMA_BF16(a0, x2, acc1[0][2], 0, 0, 0);                  \
        acc1[1][2] = MFMA_BF16(a1, x2, acc1[1][2], 0, 0, 0);                  \
        acc1[2][2] = MFMA_BF16(a2, x2, acc1[2][2], 0, 0, 0);                  \
        acc1[3][2] = MFMA_BF16(a3, x2, acc1[3][2], 0, 0, 0);                  \
        acc1[0][3] = MFMA_BF16(a0, x3, acc1[0][3], 0, 0, 0);                  \
        acc1[1][3] = MFMA_BF16(a1, x3, acc1[1][3], 0, 0, 0);                  \
        acc1[2][3] = MFMA_BF16(a2, x3, acc1[2][3], 0, 0, 0);                  \
        acc1[3][3] = MFMA_BF16(a3, x3, acc1[3][3], 0, 0, 0);                  \
        __builtin_amdgcn_s_setprio(0);                                        \
        asm volatile("s_waitcnt lgkmcnt(0)" ::: "memory");                    \
        __builtin_amdgcn_sched_barrier(0);                                    \
        __builtin_amdgcn_s_setprio(1);                                        \
        acc2[0][0] = MFMA_BF16(a0, y0, acc2[0][0], 0, 0, 0);                  \
        acc2[1][0] = MFMA_BF16(a1, y0, acc2[1][0], 0, 0, 0);                  \
        acc2[2][0] = MFMA_BF16(a2, y0, acc2[2][0], 0, 0, 0);                  \
        acc2[3][0] = MFMA_BF16(a3, y0, acc2[3][0], 0, 0, 0);                  \
        acc2[0][1] = MFMA_BF16(a0, y1, acc2[0][1], 0, 0, 0);                  \
        acc2[1][1] = MFMA_BF16(a1, y1, acc2[1][1], 0, 0, 0);                  \
        acc2[2][1] = MFMA_BF16(a2, y1, acc2[2][1], 0, 0, 0);                  \
        acc2[3][1] = MFMA_BF16(a3, y1, acc2[3][1], 0, 0, 0);                  \
        acc2[0][2] = MFMA_BF16(a0, y2, acc2[0][2], 0, 0, 0);                  \
        acc2[1][2] = MFMA_BF16(a1, y2, acc2[1][2], 0, 0, 0);                  \
        acc2[2][2] = MFMA_BF16(a2, y2, acc2[2][2], 0, 0, 0);                  \
        acc2[3][2] = MFMA_BF16(a3, y2, acc2[3][2], 0, 0, 0);                  \
        acc2[0][3] = MFMA_BF16(a0, y3, acc2[0][3], 0, 0, 0);                  \
        acc2[1][3] = MFMA_BF16(a1, y3, acc2[1][3], 0, 0, 0);                  \
        acc2[2][3] = MFMA_BF16(a2, y3, acc2[2][3], 0, 0, 0);                  \
        acc2[3][3] = MFMA_BF16(a3, y3, acc2[3][3], 0, 0, 0);                  \
        __builtin_amdgcn_s_setprio(0);                                        \
        asm volatile("s_barrier" ::: "memory");                               \
    }

template<bool STEP>
__global__ __launch_bounds__(512, 2) void ltc_gemm(
    const unsigned short* __restrict__ A,
    const unsigned short* __restrict__ B1,
    const unsigned short* __restrict__ B2,
    const unsigned short* __restrict__ GXID,   // native layout, 8 bf16/slot
    const float* __restrict__ h_init,          // row-major f32 (step 0 only)
    float* __restrict__ h_nat,                 // native f32 state, in-place
    const float* __restrict__ log_tau,
    float* __restrict__ h_out,                 // final step: d_out half 0
    float* __restrict__ h_out2,                // final step: d_out half 1
    unsigned short* __restrict__ hbf_out,      // row-major bf16 (next A)
    const float* __restrict__ bias1, const float* __restrict__ bias2,
    unsigned short* __restrict__ GXID_out)     // pre-kernel output
{
    __shared__ __attribute__((aligned(16))) unsigned short SMEM[65536]; // 128 KB

    const int tid = threadIdx.x;
    const int w = tid >> 6, l = tid & 63;
    // bijective XCD swizzle (GRID % 8 == 0)
    const int bid = (blockIdx.x & 7) * (GRID / 8) + (blockIdx.x >> 3);
    const int mt = bid / NT, nt = bid % NT;
    const int m0 = mt * BM, n0 = nt * BN;
    const int wm = (w >> 1) * 64, wn = (w & 1) * 64;
    const int lm = l & 15, lq = l >> 4;

    // staging lanes: gload round = 16 rows x 4 slots of 16B; lane l -> row
    // l>>2, phys slot l&3, fetching global slot (l&3)^((row>>1)&3).
    const int lrg = l >> 2;
    const int gsl = (l & 3) ^ ((lrg >> 1) & 3);
    const unsigned short* sA  = A  + (size_t)(m0 + w * 32 + lrg) * K_DIM + gsl * 8;
    const unsigned short* sB1 = B1 + (size_t)(n0 + w * 16 + lrg) * K_DIM + gsl * 8;
    const unsigned short* sB2 = B2 + (size_t)(n0 + w * 16 + lrg) * K_DIM + gsl * 8;
    const int dA = w * 1024;   // elem off inside A buffer (wave stages 32 rows)
    const int dB = w * 512;    // elem off inside B buffers (wave stages 16 rows)

    // fragment read base byte addrs (swizzled): row = base16+lm, slot lq
    const int phys = lq ^ ((lm >> 1) & 3);
    const unsigned smem0 = (unsigned)(uintptr_t)&SMEM[0];
    const unsigned rdA  = smem0 +          (wm + lm) * 64 + phys * 16;
    const unsigned rdB1 = smem0 + 65536 + (wn + lm) * 64 + phys * 16;
    const unsigned rdB2 = smem0 + 98304 + (wn + lm) * 64 + phys * 16;

    f32x4 acc1[4][4], acc2[4][4];
    f32x4 z4 = {0.f, 0.f, 0.f, 0.f};
    #pragma unroll
    for (int i = 0; i < 4; i++)
        #pragma unroll
        for (int j = 0; j < 4; j++) { acc1[i][j] = z4; acc2[i][j] = z4; }

    // prologue: stage tiles 0,1,2 into bufs 0,1,2 (12 loads in flight)
    STAGE4(0, 0); STAGE4(1, 32); STAGE4(2, 64);

    #pragma unroll 1
    for (int tb = 0; tb < NKT - 4; tb += 4) {   // t = 0..27
        const int ke = (tb + 3) * BK;
        KITER(0, "12", true, 3, ke);
        KITER(1, "12", true, 0, ke + 32);
        KITER(2, "12", true, 1, ke + 64);
        KITER(3, "12", true, 2, ke + 96);
    }
    KITER(0, "12", true, 3, (NKT - 1) * BK);    // t = 28, stage tile 31
    KITER(1, "8",  false, 0, 0);                // t = 29
    KITER(2, "4",  false, 0, 0);                // t = 30
    KITER(3, "0",  false, 0, 0);                // t = 31

    // epilogue: C/D layout col=lane&15, row=(lane>>4)*4+r  [m89-verified]
    constexpr float subdt = 1.0f / (float)ODE_STEPS;
    const size_t wslot = (((size_t)bid * 8 + w) * 16) * 64 + l;

    float pc1[4], pc2[4];   // per-ni hoisted: scale (STEP) or biases (!STEP)
    #pragma unroll
    for (int ni = 0; ni < 4; ni++) {
        const int gn = n0 + wn + ni * 16 + lm;
        if (STEP) {
            pc1[ni] = subdt * __expf(-log_tau[gn]);
        } else {
            pc1[ni] = bias1[gn];
            pc2[ni] = bias2[gn];
        }
    }

    #pragma unroll
    for (int mi = 0; mi < 4; mi++) {
        #pragma unroll
        for (int ni = 0; ni < 4; ni++) {
            const int gmb = m0 + wm + mi * 16 + lq * 4;
            const int gn  = n0 + wn + ni * 16 + lm;
            const size_t slot = wslot + (size_t)(mi * 4 + ni) * 64;
            if (STEP) {
                const float sc = pc1[ni];
                u16x8 gi = *(const u16x8*)&GXID[slot * 8];
                f32x4 st;
                if (h_init) {
                    #pragma unroll
                    for (int r = 0; r < 4; r++)
                        st[r] = h_init[(size_t)(gmb + r) * HIDC + gn];
                } else {
                    st = *(const f32x4*)&h_nat[slot * 4];
                }
                f32x4 hn;
                #pragma unroll
                for (int r = 0; r < 4; r++) {
                    float gx = bf2f((unsigned short)gi[r])     + acc1[mi][ni][r];
                    float dr = bf2f((unsigned short)gi[4 + r]) + acc2[mi][ni][r];
                    float gt = fast_tanh(dr) / (1.0f + __expf(-gx));
                    hn[r] = fmaf(sc, gt - st[r], st[r]);
                }
                if (h_out) {
                    #pragma unroll
                    for (int r = 0; r < 4; r++) {
                        size_t idx = (size_t)(gmb + r) * HIDC + gn;
                        h_out[idx]  = hn[r];
                        h_out2[idx] = hn[r];
                    }
                } else {
                    *(f32x4*)&h_nat[slot * 4] = hn;
                    #pragma unroll
                    for (int r = 0; r < 4; r++)
                        hbf_out[(size_t)(gmb + r) * HIDC + gn] = f2bf(hn[r]);
                }
            } else {
                u16x8 o;
                #pragma unroll
                for (int r = 0; r < 4; r++) {
                    o[r]     = f2bf(acc1[mi][ni][r] + pc1[ni]);
                    o[4 + r] = f2bf(acc2[mi][ni][r] + pc2[ni]);
                }
                *(u16x8*)&GXID_out[slot * 8] = o;
            }
        }
    }
}

extern "C" void kernel_launch(void* const* d_in, const int* in_sizes, int n_in,
                              void* d_out, int out_size, void* d_ws, size_t ws_size,
                              hipStream_t stream)
{
    const float* x    = (const float*)d_in[0];
    const float* h    = (const float*)d_in[1];
    const float* ltau = (const float*)d_in[2];
    const float* winw = (const float*)d_in[3];
    const float* winb = (const float*)d_in[4];
    const float* wrec = (const float*)d_in[5];
    const float* wg   = (const float*)d_in[6];
    const float* wgb  = (const float*)d_in[7];

    char* ws = (char*)d_ws;
    unsigned short* x_bf    = (unsigned short*)ws; ws += XN * 2;
    unsigned short* h_bf0   = (unsigned short*)ws; ws += HN * 2;
    unsigned short* h_bf1   = (unsigned short*)ws; ws += HN * 2;
    unsigned short* win_bf  = (unsigned short*)ws; ws += WINN * 2;
    unsigned short* wrec_bf = (unsigned short*)ws; ws += WRECN * 2;
    unsigned short* wgx_bf  = (unsigned short*)ws; ws += WINN * 2;
    unsigned short* wgh_bf  = (unsigned short*)ws; ws += WRECN * 2;
    unsigned short* GXID    = (unsigned short*)ws; ws += HN * 2 * 2;  // 32 MB
    float*          h_nat   = (float*)ws;          ws += HN * 4;      // 32 MB

    float* hout  = (float*)d_out;
    float* hout2 = hout + (size_t)B_DIM * HIDC;

    convert_all<<<(int)(TOTQ / 256), 256, 0, stream>>>(
        x, h, winw, wrec, wg, x_bf, h_bf0, win_bf, wrec_bf, wgx_bf, wgh_bf);

    // pre-loop: GXID = pack(x@Wgx^T + wgb, x@Win^T + winb) in native layout
    ltc_gemm<false><<<GRID, 512, 0, stream>>>(
        x_bf, wgx_bf, win_bf,
        nullptr, nullptr, nullptr, nullptr, nullptr, nullptr, nullptr,
        wgb, winb, GXID);

    unsigned short* hbf[2] = {h_bf0, h_bf1};
    for (int s = 0; s < ODE_STEPS; s++) {
        const bool last = (s == ODE_STEPS - 1);
        ltc_gemm<true><<<GRID, 512, 0, stream>>>(
            hbf[s & 1], wgh_bf, wrec_bf,
            GXID,
            (s == 0) ? h : nullptr,
            h_nat, ltau,
            last ? hout : nullptr, last ? hout2 : nullptr,
            last ? nullptr : hbf[(s + 1) & 1],
            nullptr, nullptr, nullptr);
    }
}